// Round 1
// baseline (42600.128 us; speedup 1.0000x reference)
//
#include <hip/hip_runtime.h>
#include <hip/hip_bf16.h>

#define Bn 16
#define Cn 128
#define Hn 72
#define Wn 200
#define Kn 9
#define PADn 4

// ---------------------------------------------------------------------------
// Row step: buf[b, o, h_out, w] += relu( sum_{i,k} buf[b, i, h_prev, w+k-4] * wgt[o,i,k] )
// conv along W (contiguous). Grid: (16 b, 4 wtiles of 64, 4 o-groups of 32). Block 256.
// ---------------------------------------------------------------------------
__global__ __launch_bounds__(256) void row_step(float* __restrict__ buf,
                                                const float* __restrict__ wgt,
                                                int h_prev, int h_out) {
    const int b   = blockIdx.x;
    const int wt  = blockIdx.y;
    const int og  = blockIdx.z;
    const int tid = threadIdx.x;
    const int lane_w = tid & 63;
    const int sub = __builtin_amdgcn_readfirstlane(tid >> 6);   // wave-uniform
    const int wbase = wt * 64;

    __shared__ float prev[Cn][72];   // columns wbase-4 .. wbase+67

    for (int idx = tid; idx < Cn * 72; idx += 256) {
        int i  = idx / 72;
        int ww = idx - i * 72;
        int gw = wbase - PADn + ww;
        float v = 0.f;
        if (gw >= 0 && gw < Wn)
            v = buf[((b * Cn + i) * Hn + h_prev) * Wn + gw];
        prev[i][ww] = v;
    }
    __syncthreads();

    const int w = wbase + lane_w;
    const int o0 = og * 32 + sub * 8;

    float acc[8];
#pragma unroll
    for (int j = 0; j < 8; ++j) acc[j] = 0.f;

    for (int i = 0; i < Cn; ++i) {
        float xv[Kn];
#pragma unroll
        for (int k = 0; k < Kn; ++k) xv[k] = prev[i][lane_w + k];
#pragma unroll
        for (int j = 0; j < 8; ++j) {
            const float* wp = wgt + ((o0 + j) * Cn + i) * Kn;
#pragma unroll
            for (int k = 0; k < Kn; ++k) acc[j] += wp[k] * xv[k];
        }
    }

    if (w < Wn) {
#pragma unroll
        for (int j = 0; j < 8; ++j) {
            float r = acc[j] > 0.f ? acc[j] : 0.f;
            buf[((b * Cn + (o0 + j)) * Hn + h_out) * Wn + w] += r;
        }
    }
}

// ---------------------------------------------------------------------------
// Col step: buf[b, o, h, w_out] += relu( sum_{i,k} buf[b, i, h+k-4, w_prev] * wgt[o,i,k] )
// conv along H (strided). Grid: (16 b, 8 o-groups of 16). Block 256 (4 waves x 4 o each).
// ---------------------------------------------------------------------------
__global__ __launch_bounds__(256) void col_step(float* __restrict__ buf,
                                                const float* __restrict__ wgt,
                                                int w_prev, int w_out) {
    const int b   = blockIdx.x;
    const int og  = blockIdx.y;
    const int tid = threadIdx.x;
    const int lane = tid & 63;
    const int wid = __builtin_amdgcn_readfirstlane(tid >> 6);   // wave-uniform

    __shared__ float prev[Cn][80];   // slot s holds value at h = s-4, zero-padded

    for (int idx = tid; idx < Cn * 80; idx += 256) {
        int i = idx / 80;
        int s = idx - i * 80;
        int h = s - PADn;
        float v = 0.f;
        if (h >= 0 && h < Hn)
            v = buf[((b * Cn + i) * Hn + h) * Wn + w_prev];
        prev[i][s] = v;
    }
    __syncthreads();

    const int o0 = og * 16 + wid * 4;

    for (int hh = lane; hh < Hn; hh += 64) {
        float acc[4] = {0.f, 0.f, 0.f, 0.f};
        for (int i = 0; i < Cn; ++i) {
            float xv[Kn];
#pragma unroll
            for (int k = 0; k < Kn; ++k) xv[k] = prev[i][hh + k];
#pragma unroll
            for (int j = 0; j < 4; ++j) {
                const float* wp = wgt + ((o0 + j) * Cn + i) * Kn;
#pragma unroll
                for (int k = 0; k < Kn; ++k) acc[j] += wp[k] * xv[k];
            }
        }
#pragma unroll
        for (int j = 0; j < 4; ++j) {
            float r = acc[j] > 0.f ? acc[j] : 0.f;
            buf[((b * Cn + (o0 + j)) * Hn + hh) * Wn + w_out] += r;
        }
    }
}

extern "C" void kernel_launch(void* const* d_in, const int* in_sizes, int n_in,
                              void* d_out, int out_size, void* d_ws, size_t ws_size,
                              hipStream_t stream) {
    const float* x  = (const float*)d_in[0];
    const float* wd = (const float*)d_in[1];
    const float* wu = (const float*)d_in[2];
    const float* wr = (const float*)d_in[3];
    const float* wl = (const float*)d_in[4];
    float* buf = (float*)d_out;

    // buf = x
    hipMemcpyAsync(buf, x, (size_t)Bn * Cn * Hn * Wn * sizeof(float),
                   hipMemcpyDeviceToDevice, stream);

    dim3 blk(256);
    dim3 rgrid(Bn, 4, 4);   // b, wtile, o-group

    // row forward sweep (down H), weights w_d
    for (int h = 1; h < Hn; ++h)
        row_step<<<rgrid, blk, 0, stream>>>(buf, wd, h - 1, h);
    // row backward sweep (up H), weights w_u
    for (int h = Hn - 2; h >= 1; --h)
        row_step<<<rgrid, blk, 0, stream>>>(buf, wu, h + 1, h);

    dim3 cgrid(Bn, 8);      // b, o-group

    // col forward sweep (right W), weights w_r
    for (int w = 1; w < Wn; ++w)
        col_step<<<cgrid, blk, 0, stream>>>(buf, wr, w - 1, w);
    // col backward sweep (left W), weights w_l
    for (int w = Wn - 2; w >= 1; --w)
        col_step<<<cgrid, blk, 0, stream>>>(buf, wl, w + 1, w);
}

// Round 3
// 14494.917 us; speedup vs baseline: 2.9390x; 2.9390x over previous
//
#include <hip/hip_runtime.h>
#include <hip/hip_bf16.h>

#define Bn 16
#define Cn 128
#define Hn 72
#define Wn 200
#define Kn 9
#define PADn 4

// ---------------------------------------------------------------------------
// Row step, layout NCHW (line = W contiguous).
// buf[b,o,h_out,w] += relu( sum_{i,k} buf[b,i,h_prev,w+k-4] * wgt[o,i,k] )
// grid (wt=2, og=8, b=16), block 512 = 64 lanes (w-pairs) x 8 subs
// subs: osub = sub&3 (4 outputs each), ihalf = sub>>2 (input-channel split)
// ---------------------------------------------------------------------------
__global__ __launch_bounds__(512) void row_step(float* __restrict__ buf,
                                                const float* __restrict__ wgt,
                                                int h_prev, int h_out) {
    const int wt  = blockIdx.x;           // 0..1, w-tile of 128
    const int og  = blockIdx.y;           // 0..7, 16 outputs each
    const int b   = blockIdx.z;           // 0..15
    const int tid = threadIdx.x;
    const int lane = tid & 63;
    const int sub  = __builtin_amdgcn_readfirstlane(tid >> 6);
    const int osub = sub & 3;
    const int ihalf = sub >> 2;

    __shared__ float prev[Cn][136];       // w-slots wt*128-4 .. wt*128+131
    __shared__ float redu[4][64][9];      // osub, lane, 8 used (+1 pad)

    const int wbase = wt * 128 - PADn;
    for (int f = tid; f < Cn * 136; f += 512) {
        int i = f / 136, s = f - i * 136;
        int gw = wbase + s;
        float v = 0.f;
        if (gw >= 0 && gw < Wn)
            v = buf[((size_t)(b * Cn + i) * Hn + h_prev) * Wn + gw];
        prev[i][s] = v;
    }
    __syncthreads();

    const int w0 = wt * 128 + lane * 2;
    const int o0 = og * 16 + osub * 4;
    const int xbase = lane * 2;

    float acc[4][2] = {};
    for (int i = 0; i < 64; ++i) {
        const int ii = ihalf * 64 + i;
        float xv[10];
#pragma unroll
        for (int c = 0; c < 5; ++c) {
            float2 t = *(const float2*)&prev[ii][xbase + 2 * c];
            xv[2 * c] = t.x; xv[2 * c + 1] = t.y;
        }
#pragma unroll
        for (int j = 0; j < 4; ++j) {
            const float* wr = wgt + ((size_t)(o0 + j) * Cn + ii) * Kn;
#pragma unroll
            for (int k = 0; k < Kn; ++k) {
                float wv = wr[k];
                acc[j][0] += wv * xv[k];
                acc[j][1] += wv * xv[k + 1];
            }
        }
    }

    if (ihalf == 1) {
#pragma unroll
        for (int j = 0; j < 4; ++j) {
            redu[osub][lane][j * 2]     = acc[j][0];
            redu[osub][lane][j * 2 + 1] = acc[j][1];
        }
    }
    __syncthreads();
    if (ihalf == 0 && w0 < Wn) {
#pragma unroll
        for (int j = 0; j < 4; ++j) {
            float a0 = acc[j][0] + redu[osub][lane][j * 2];
            float a1 = acc[j][1] + redu[osub][lane][j * 2 + 1];
            a0 = fmaxf(a0, 0.f);
            a1 = fmaxf(a1, 0.f);
            float2* p = (float2*)&buf[((size_t)(b * Cn + o0 + j) * Hn + h_out) * Wn + w0];
            float2 old = *p;
            old.x += a0; old.y += a1;
            *p = old;
        }
    }
}

// ---------------------------------------------------------------------------
// Col step. TRANS=true: buf is NCWH (line = H contiguous). TRANS=false:
// fallback on NCHW (strided, correct but slow — only if ws too small).
// buf[b,o,*,h] += relu( sum_{i,k} buf[b,i,*prev,h+k-4] * wgt[o,i,k] )
// grid (b=16, og=32), block 256 = 64 lanes x 4 subs.
// Each block owns exactly ONE b slice => no cross-b lane span (round-2 bug).
// Lane = h-pair, active lanes 0..35 (72 h). osub = sub&1 (2 outputs each),
// ihalf = sub>>1 (input-channel split, LDS reduction).
// ---------------------------------------------------------------------------
template <bool TRANS>
__global__ __launch_bounds__(256) void col_step(float* __restrict__ buf,
                                                const float* __restrict__ wgt,
                                                int w_prev, int w_out) {
    const int b   = blockIdx.x;           // 0..15
    const int og  = blockIdx.y;           // 0..31, 4 outputs each
    const int tid = threadIdx.x;
    const int lane = tid & 63;
    const int sub  = __builtin_amdgcn_readfirstlane(tid >> 6);
    const int osub = sub & 1;
    const int ihalf = sub >> 1;

    __shared__ float prev[Cn][80];        // h-slot s = h+4, pads zeroed
    __shared__ float redu[2][64][5];

    for (int f = tid; f < Cn * 80; f += 256) {
        int i = f / 80, s = f - i * 80;
        int h = s - PADn;
        float v = 0.f;
        if (h >= 0 && h < Hn) {
            if (TRANS)
                v = buf[((size_t)(b * Cn + i) * Wn + w_prev) * Hn + h];
            else
                v = buf[((size_t)(b * Cn + i) * Hn + h) * Wn + w_prev];
        }
        prev[i][s] = v;
    }
    __syncthreads();

    const int h0 = lane * 2;              // 0..70 for active lanes
    const int o0 = og * 4 + osub * 2;
    const bool active = lane < 36;

    float acc[2][2] = {};
    if (active) {
        for (int i = 0; i < 64; ++i) {
            const int ii = ihalf * 64 + i;
            const float* pp = &prev[ii][h0];
            float xv[10];
#pragma unroll
            for (int c = 0; c < 5; ++c) {
                float2 t = *(const float2*)&pp[2 * c];
                xv[2 * c] = t.x; xv[2 * c + 1] = t.y;
            }
#pragma unroll
            for (int j = 0; j < 2; ++j) {
                const float* wr = wgt + ((size_t)(o0 + j) * Cn + ii) * Kn;
#pragma unroll
                for (int k = 0; k < Kn; ++k) {
                    float wv = wr[k];
                    acc[j][0] += wv * xv[k];
                    acc[j][1] += wv * xv[k + 1];
                }
            }
        }
    }

    if (ihalf == 1 && active) {
#pragma unroll
        for (int j = 0; j < 2; ++j) {
            redu[osub][lane][j * 2]     = acc[j][0];
            redu[osub][lane][j * 2 + 1] = acc[j][1];
        }
    }
    __syncthreads();
    if (ihalf == 0 && active) {
#pragma unroll
        for (int j = 0; j < 2; ++j) {
            float a0 = fmaxf(acc[j][0] + redu[osub][lane][j * 2], 0.f);
            float a1 = fmaxf(acc[j][1] + redu[osub][lane][j * 2 + 1], 0.f);
            if (TRANS) {
                float2* p = (float2*)&buf[((size_t)(b * Cn + o0 + j) * Wn + w_out) * Hn + h0];
                float2 old = *p;
                old.x += a0; old.y += a1;
                *p = old;
            } else {
                buf[((size_t)(b * Cn + o0 + j) * Hn + h0) * Wn + w_out]     += a0;
                buf[((size_t)(b * Cn + o0 + j) * Hn + h0 + 1) * Wn + w_out] += a1;
            }
        }
    }
}

// ---------------------------------------------------------------------------
// Tiled transpose of the trailing two dims: in [bc][S1][S2] -> out [bc][S2][S1]
// ---------------------------------------------------------------------------
__global__ __launch_bounds__(256) void transpose_hw(const float* __restrict__ in,
                                                    float* __restrict__ out,
                                                    int S1, int S2) {
    __shared__ float tile[32][33];
    const int bc = blockIdx.z;
    const int s1_0 = blockIdx.y * 32, s2_0 = blockIdx.x * 32;
    const int tx = threadIdx.x, ty = threadIdx.y;     // 32 x 8
    const float* ip = in + (size_t)bc * S1 * S2;
    float* op = out + (size_t)bc * S1 * S2;
#pragma unroll
    for (int r = 0; r < 32; r += 8) {
        int s1 = s1_0 + ty + r, s2 = s2_0 + tx;
        if (s1 < S1 && s2 < S2) tile[ty + r][tx] = ip[(size_t)s1 * S2 + s2];
    }
    __syncthreads();
#pragma unroll
    for (int r = 0; r < 32; r += 8) {
        int s2 = s2_0 + ty + r, s1 = s1_0 + tx;
        if (s2 < S2 && s1 < S1) op[(size_t)s2 * S1 + s1] = tile[tx][ty + r];
    }
}

extern "C" void kernel_launch(void* const* d_in, const int* in_sizes, int n_in,
                              void* d_out, int out_size, void* d_ws, size_t ws_size,
                              hipStream_t stream) {
    const float* x  = (const float*)d_in[0];
    const float* wd = (const float*)d_in[1];
    const float* wu = (const float*)d_in[2];
    const float* wr = (const float*)d_in[3];
    const float* wl = (const float*)d_in[4];
    float* buf  = (float*)d_out;           // NCHW state
    float* tbuf = (float*)d_ws;            // NCWH state (needs ~118 MB)

    const size_t total = (size_t)Bn * Cn * Hn * Wn;
    const bool use_ws = (ws_size >= total * sizeof(float));  // constant across calls

    // buf = x
    hipMemcpyAsync(buf, x, total * sizeof(float), hipMemcpyDeviceToDevice, stream);

    // ---- row sweeps in NCHW ----
    dim3 rblk(512);
    dim3 rgrid(2, 8, Bn);
    for (int h = 1; h < Hn; ++h)
        row_step<<<rgrid, rblk, 0, stream>>>(buf, wd, h - 1, h);
    for (int h = Hn - 2; h >= 1; --h)
        row_step<<<rgrid, rblk, 0, stream>>>(buf, wu, h + 1, h);

    dim3 cblk(256);
    dim3 cgrid(Bn, 32);

    if (use_ws) {
        // ---- transpose NCHW -> NCWH ----
        dim3 tblk(32, 8);
        dim3 tg1((Wn + 31) / 32, (Hn + 31) / 32, Bn * Cn);
        transpose_hw<<<tg1, tblk, 0, stream>>>(buf, tbuf, Hn, Wn);

        // ---- col sweeps in NCWH (coalesced) ----
        for (int w = 1; w < Wn; ++w)
            col_step<true><<<cgrid, cblk, 0, stream>>>(tbuf, wr, w - 1, w);
        for (int w = Wn - 2; w >= 1; --w)
            col_step<true><<<cgrid, cblk, 0, stream>>>(tbuf, wl, w + 1, w);

        // ---- transpose back NCWH -> NCHW into d_out ----
        dim3 tg2((Hn + 31) / 32, (Wn + 31) / 32, Bn * Cn);
        transpose_hw<<<tg2, tblk, 0, stream>>>(tbuf, buf, Wn, Hn);
    } else {
        // ---- fallback: col sweeps directly on NCHW (strided staging) ----
        for (int w = 1; w < Wn; ++w)
            col_step<false><<<cgrid, cblk, 0, stream>>>(buf, wr, w - 1, w);
        for (int w = Wn - 2; w >= 1; --w)
            col_step<false><<<cgrid, cblk, 0, stream>>>(buf, wl, w + 1, w);
    }
}